// Round 7
// baseline (450.174 us; speedup 1.0000x reference)
//
#include <hip/hip_runtime.h>
#include <math.h>

// (N,C,D,H,W)=(2,32,48,48,48), K=3, T=8. All fp32 in/out (verified R5).
// R7: fp16 LDS tile (12.2KB), token-quadrant XOR swizzle, cbuf col swizzle.
// LDS 45056 -> 36864 B => 4 blocks/CU (was 3); kills 8-way token-write conflict.
#define NB   2
#define CH   32
#define DHW  (48*48*48)
#define TT   8
#define EPSF 1e-6f

#define TILE_N   1521            // 13*13*9 halo tile (elements)
#define TILE_STR 1524            // fp16 elements per channel (pad 3)
#define GROUPS   8               // 32 ch / 4 per group

// LDS layout (bytes): tokens [0,20480) = 256*80 ; tile fp16 [20480,32672)
// cbuf aliases [0,36864) = 256 rows * 36 floats (used only after final barrier)
#define TOK_OFF  0
#define TOK_STR  80              // 64B tokens + 16B pad; 16B-aligned quadrants
#define TILE_OFF 20480
#define SMEM_SZ  36864

// ws layout (float idx): Bt bf16 [0,4096) floats (=8192 ushort), wf 4096, bf 4480, bm 4492
#define WS_BT_F 0
#define WS_WF   4096
#define WS_BF   4480
#define WS_BM   4492

typedef __attribute__((ext_vector_type(8))) short short8;
typedef __attribute__((ext_vector_type(4))) float floatx4;

__device__ __forceinline__ unsigned short f2bf(float f) {
    unsigned u = __float_as_uint(f);
    u += 0x7FFFu + ((u >> 16) & 1u);           // RNE
    return (unsigned short)(u >> 16);
}
__device__ __forceinline__ unsigned pk2(float a, float b) {
    return (unsigned)f2bf(a) | ((unsigned)f2bf(b) << 16);
}

__global__ __launch_bounds__(256) void prep_kernel(
        const float* __restrict__ w_field,
        const float* __restrict__ b_field,
        const float* __restrict__ gates,
        const float* __restrict__ w_mix,
        const float* __restrict__ b_mix,
        float* __restrict__ ws) {
    int i = blockIdx.x * 256 + threadIdx.x;    // grid 32*256 = 8192
    // Bt[n][k] bf16, k = c*8 + t, value = sigmoid(gates[t]) * w_mix[n, t*32+c]
    {
        int n = i >> 8, k = i & 255, c = k >> 3, t = k & 7;
        float sg = 1.0f / (1.0f + expf(-gates[t]));
        ((unsigned short*)(ws + WS_BT_F))[n * 256 + k] = f2bf(sg * w_mix[n * 256 + t * 32 + c]);
    }
    if (i < 384) { int c = i / 12, o = i - c * 12; ws[WS_WF + i] = w_field[o * 32 + c]; }
    if (i < 12)  ws[WS_BF + i] = b_field[i];
    if (i < 32)  ws[WS_BM + i] = b_mix[i];
}

__global__ __launch_bounds__(256) void geo_main(
        const float* __restrict__ x,
        const float* __restrict__ ws,
        float* __restrict__ out) {
    __shared__ __align__(16) char smem[SMEM_SZ];
    char*      tokb  = smem + TOK_OFF;
    _Float16*  tileH = (_Float16*)(smem + TILE_OFF);
    float*     cbuf  = (float*)smem;           // alias, post-loop only

    const int tid = threadIdx.x;
    const int b  = blockIdx.x;
    const int bx = b % 6, by = (b / 6) % 6, bz = (b / 36) % 12, n = b / 432;
    const int lx = tid & 7, ly = (tid >> 3) & 7, lz = tid >> 6;
    const int w = bx * 8 + lx, h = by * 8 + ly, d = bz * 4 + lz;
    const int xlo = bx * 8 - 2, ylo = by * 8 - 2, zlo = bz * 4 - 2;
    const int lane = tid & 63, w64 = tid & 192;

    const float* xn = x + (size_t)n * CH * DHW;

    // ---- channel-invariant halo-load offsets ----
    int goff[6];
#pragma unroll
    for (int i = 0; i < 6; ++i) {
        int e  = tid + i * 256;
        int ee = (e < TILE_N) ? e : 0;
        int tz = ee / 169; int r0 = ee - tz * 169;
        int ty = r0 / 13;  int tx = r0 - ty * 13;
        int zg = min(max(zlo + tz, 0), 47);
        int yg = min(max(ylo + ty, 0), 47);
        int xg = min(max(xlo + tx, 0), 47);
        goff[i] = (zg * 48 + yg) * 48 + xg;
    }

    // ---- phase A: f[12] = w_field @ x(:,pos) + b_field ----
    const int pos = (d * 48 + h) * 48 + w;
    float f[12];
#pragma unroll
    for (int o = 0; o < 12; ++o) f[o] = ws[WS_BF + o];
    for (int c = 0; c < CH; ++c) {
        float xv = xn[c * DHW + pos];
        const float* wf = ws + WS_WF + c * 12;
#pragma unroll
        for (int o = 0; o < 12; ++o) f[o] = fmaf(wf[o], xv, f[o]);
    }

    // ---- per-voxel sample parameters ----
    float fxa[6], fya[6], fza[6];
    int a00[6], a01[6], a10[6], a11[6];
    float uxk[3], uyk[3], uzk[3], irk[3], ir2k[3];
    const float cscale = 48.0f / (48.0f + EPSF);
#pragma unroll
    for (int k = 0; k < 3; ++k) {
        float vx = f[4*k], vy = f[4*k+1], vz = f[4*k+2], s = f[4*k+3];
        float inv = 1.0f / sqrtf(vx*vx + vy*vy + vz*vz + EPSF);
        float ux = vx * inv, uy = vy * inv, uz = vz * inv;
        float r  = 0.5f + 1.5f / (1.0f + expf(-s));
        uxk[k] = ux; uyk[k] = uy; uzk[k] = uz;
        float ir = 1.0f / (r + EPSF); irk[k] = ir; ir2k[k] = ir * ir;
#pragma unroll
        for (int sgn = 0; sgn < 2; ++sgn) {
            int   si = 2 * k + sgn;
            float sf = sgn ? -1.0f : 1.0f;
            float txr = (float)w + sf * r * ux * cscale;
            float tyr = (float)h + sf * r * uy * cscale;
            float tzr = (float)d + sf * r * uz * cscale;
            float cx = fabsf(txr + 0.5f); float ix = fminf(cx, 96.0f - cx) - 0.5f;
            float cy = fabsf(tyr + 0.5f); float iy = fminf(cy, 96.0f - cy) - 0.5f;
            float cz = fabsf(tzr + 0.5f); float iz = fminf(cz, 96.0f - cz) - 0.5f;
            float x0f = floorf(ix), y0f = floorf(iy), z0f = floorf(iz);
            float fx = ix - x0f, fy = iy - y0f, fz = iz - z0f;
            int x0 = min(max((int)x0f, 0), 47); int x1 = min(x0 + 1, 47);
            int y0 = min(max((int)y0f, 0), 47); int y1 = min(y0 + 1, 47);
            int z0 = min(max((int)z0f, 0), 47); int z1 = min(z0 + 1, 47);
            fxa[si] = (x1 == x0) ? 0.0f : fx;   // reference's clipped-x1 semantics
            fya[si] = fy; fza[si] = fz;
            int lz0 = z0 - zlo, lz1 = z1 - zlo;
            int ly0 = y0 - ylo, ly1 = y1 - ylo;
            int lx0 = x0 - xlo;
            a00[si] = (lz0 * 13 + ly0) * 13 + lx0;
            a01[si] = (lz0 * 13 + ly1) * 13 + lx0;
            a10[si] = (lz1 * 13 + ly0) * 13 + lx0;
            a11[si] = (lz1 * 13 + ly1) * 13 + lx0;
        }
    }

    // ---- stage group 0 tiles (fp32 -> fp16) ----
    {
        float ld[24];
#pragma unroll
        for (int cg = 0; cg < 4; ++cg) {
            const float* xc = xn + cg * DHW;
#pragma unroll
            for (int i = 0; i < 6; ++i) ld[cg * 6 + i] = xc[goff[i]];
        }
#pragma unroll
        for (int cg = 0; cg < 4; ++cg)
#pragma unroll
            for (int i = 0; i < 6; ++i) {
                int e = tid + i * 256;
                if (e < TILE_N) tileH[cg * TILE_STR + e] = (_Float16)ld[cg * 6 + i];
            }
    }
    __syncthreads();

    floatx4 acc[4][2];
#pragma unroll
    for (int mt = 0; mt < 4; ++mt)
#pragma unroll
        for (int nt = 0; nt < 2; ++nt) acc[mt][nt] = (floatx4){0.f, 0.f, 0.f, 0.f};

    const int self = ((lz + 2) * 13 + (ly + 2)) * 13 + (lx + 2);
    const unsigned short* bt = (const unsigned short*)(ws + WS_BT_F);
    const int tokq = (tid >> 3) & 3;           // writer quadrant swizzle key

    for (int g = 0; g < GROUPS; ++g) {
        float nld[24];
        if (g < GROUPS - 1) {
            const float* xg = xn + (g + 1) * 4 * DHW;
#pragma unroll
            for (int cg = 0; cg < 4; ++cg) {
                const float* xc = xg + cg * DHW;
#pragma unroll
                for (int i = 0; i < 6; ++i) nld[cg * 6 + i] = xc[goff[i]];
            }
        }
        // ---- compute tokens for 4 channels, pack to LDS (swizzled quadrant) ----
#pragma unroll
        for (int cg = 0; cg < 4; ++cg) {
            const _Float16* tb = tileH + cg * TILE_STR;
            float xv = (float)tb[self];
            float val[6];
#pragma unroll
            for (int si = 0; si < 6; ++si) {
                int b00 = a00[si], b01 = a01[si], b10 = a10[si], b11 = a11[si];
                float v000 = (float)tb[b00], v001 = (float)tb[b00 + 1];
                float v010 = (float)tb[b01], v011 = (float)tb[b01 + 1];
                float v100 = (float)tb[b10], v101 = (float)tb[b10 + 1];
                float v110 = (float)tb[b11], v111 = (float)tb[b11 + 1];
                float fx = fxa[si], fy = fya[si], fz = fza[si];
                float c00 = fmaf(fx, v001 - v000, v000);
                float c01 = fmaf(fx, v011 - v010, v010);
                float c10 = fmaf(fx, v101 - v100, v100);
                float c11 = fmaf(fx, v111 - v110, v110);
                float c0  = fmaf(fy, c01 - c00, c00);
                float c1  = fmaf(fy, c11 - c10, c10);
                val[si]   = fmaf(fz, c1 - c0, c0);
            }
            float t1, t2, t3, gx, gy, gz, l;
            {
                float sp, sm, d1;
                sp = val[0]; sm = val[1]; t1 = 0.5f * (sp + sm);
                d1 = 0.5f * (sp - sm) * irk[0];
                gx = uxk[0] * d1; gy = uyk[0] * d1; gz = uzk[0] * d1;
                l  = (sp + sm - 2.0f * xv) * ir2k[0];
                sp = val[2]; sm = val[3]; t2 = 0.5f * (sp + sm);
                d1 = 0.5f * (sp - sm) * irk[1];
                gx = fmaf(uxk[1], d1, gx); gy = fmaf(uyk[1], d1, gy); gz = fmaf(uzk[1], d1, gz);
                l  = fmaf(sp + sm - 2.0f * xv, ir2k[1], l);
                sp = val[4]; sm = val[5]; t3 = 0.5f * (sp + sm);
                d1 = 0.5f * (sp - sm) * irk[2];
                gx = fmaf(uxk[2], d1, gx); gy = fmaf(uyk[2], d1, gy); gz = fmaf(uzk[2], d1, gz);
                l  = fmaf(sp + sm - 2.0f * xv, ir2k[2], l);
            }
            uint4 tw;
            tw.x = pk2(xv, t1);
            tw.y = pk2(t2, t3);
            tw.z = pk2(gx, gy);
            tw.w = pk2(gz, l * (1.0f / 3.0f));
            int qe = cg ^ tokq;                // kill 8-way bank conflict
            *(uint4*)(tokb + tid * TOK_STR + qe * 16) = tw;
        }
        __syncthreads();   // tokens visible; tile reads complete

        if (g < GROUPS - 1) {
#pragma unroll
            for (int cg = 0; cg < 4; ++cg)
#pragma unroll
                for (int i = 0; i < 6; ++i) {
                    int e = tid + i * 256;
                    if (e < TILE_N) tileH[cg * TILE_STR + e] = (_Float16)nld[cg * 6 + i];
                }
        }
        // ---- MFMA: K-chunk g (k = g*32 .. g*32+31) ----
        int q = lane >> 4, nlo = lane & 15;
        short8 b0 = *(const short8*)(bt + (nlo * 256 + g * 32 + q * 8));
        short8 b1 = *(const short8*)(bt + ((nlo + 16) * 256 + g * 32 + q * 8));
#pragma unroll
        for (int mt = 0; mt < 4; ++mt) {
            int row = w64 + mt * 16 + nlo;
            int qe  = q ^ ((row >> 3) & 3);
            short8 a = *(const short8*)(tokb + row * TOK_STR + qe * 16);
            acc[mt][0] = __builtin_amdgcn_mfma_f32_16x16x32_bf16(a, b0, acc[mt][0], 0, 0, 0);
            acc[mt][1] = __builtin_amdgcn_mfma_f32_16x16x32_bf16(a, b1, acc[mt][1], 0, 0, 0);
        }
        __syncthreads();   // tile writes visible; token reads complete
    }

    // ---- C writeback via LDS (col-swizzled, conflict-free reads) ----
    {
        int q = lane >> 4, nlo = lane & 15;
#pragma unroll
        for (int mt = 0; mt < 4; ++mt)
#pragma unroll
            for (int nt = 0; nt < 2; ++nt)
#pragma unroll
                for (int r = 0; r < 4; ++r) {
                    int v = w64 + mt * 16 + q * 4 + r;
                    int col = nt * 16 + nlo;
                    cbuf[v * 36 + (col ^ (v & 31))] = acc[mt][nt][r];
                }
    }
    __syncthreads();

    // ---- epilogue: out = x + delta + b_mix (coalesced) ----
    const float* dr = cbuf + tid * 36;
    float* on = out + (size_t)n * CH * DHW;
#pragma unroll
    for (int o = 0; o < 32; ++o)
        on[o * DHW + pos] = xn[o * DHW + pos] + dr[o ^ (tid & 31)] + ws[WS_BM + o];
}

extern "C" void kernel_launch(void* const* d_in, const int* in_sizes, int n_in,
                              void* d_out, int out_size, void* d_ws, size_t ws_size,
                              hipStream_t stream) {
    const float *x = (const float*)d_in[0], *w_field = (const float*)d_in[1],
                *b_field = (const float*)d_in[2], *gates = (const float*)d_in[3],
                *w_mix = (const float*)d_in[4], *b_mix = (const float*)d_in[5];
    for (int i = 0; i < n_in; ++i) {
        switch (in_sizes[i]) {
            case NB * CH * DHW: x       = (const float*)d_in[i]; break;
            case 12 * CH:       w_field = (const float*)d_in[i]; break;
            case 12:            b_field = (const float*)d_in[i]; break;
            case TT:            gates   = (const float*)d_in[i]; break;
            case CH * TT * CH:  w_mix   = (const float*)d_in[i]; break;
            case CH:            b_mix   = (const float*)d_in[i]; break;
            default: break;
        }
    }
    float* ws = (float*)d_ws;
    prep_kernel<<<32, 256, 0, stream>>>(w_field, b_field, gates, w_mix, b_mix, ws);
    geo_main<<<864, 256, 0, stream>>>(x, ws, (float*)d_out);
}

// Round 9
// 178.328 us; speedup vs baseline: 2.5244x; 2.5244x over previous
//
#include <hip/hip_runtime.h>
#include <math.h>

// (N,C,D,H,W)=(2,32,48,48,48), K=3, T=8. All fp32 in/out (verified R5).
// R9 = R8 + compile fix: tile = fp16 PAIRS in 32-bit LDS words (2 ch/word),
// ds_read_b32 gather, packed v_pk fp16 trilinear. LDS 36 KB -> 4 blocks/CU.
// Token XOR swizzle + cbuf swizzle kept (R7 — verified conflicts 2e7 -> 4e5).
#define NB   2
#define CH   32
#define DHW  (48*48*48)
#define TT   8
#define EPSF 1e-6f

#define TILE_N   1521            // 13*13*9 halo tile (voxel words; 1 word = 2 ch fp16)
#define TILE_WSTR 1522           // words per plane (+1 pad)
#define GROUPS   8               // 32 ch / 4 per group (= 2 pair-planes)

// LDS layout (bytes): tokens [0,20480) = 256*80 ; tile pairs [20480,32656)
// cbuf aliases [0,36864) = 256 rows * 36 floats (used only after final barrier)
#define TOK_OFF  0
#define TOK_STR  80              // 64B tokens + 16B pad
#define TILE_OFF 20480
#define SMEM_SZ  36864

// ws layout (float idx): Bt bf16 [0,4096) floats (=8192 ushort), wf 4096, bf 4480, bm 4492
#define WS_BT_F 0
#define WS_WF   4096
#define WS_BF   4480
#define WS_BM   4492

typedef __attribute__((ext_vector_type(8))) short short8;
typedef __attribute__((ext_vector_type(4))) float floatx4;
typedef __attribute__((ext_vector_type(2))) _Float16 h2;

__device__ __forceinline__ h2 pkrtz(float a, float b) {
    return __builtin_bit_cast(h2, __builtin_amdgcn_cvt_pkrtz(a, b));
}
__device__ __forceinline__ unsigned short f2bf(float f) {
    unsigned u = __float_as_uint(f);
    u += 0x7FFFu + ((u >> 16) & 1u);           // RNE
    return (unsigned short)(u >> 16);
}
__device__ __forceinline__ unsigned pk2(float a, float b) {
    return (unsigned)f2bf(a) | ((unsigned)f2bf(b) << 16);
}

__global__ __launch_bounds__(256) void prep_kernel(
        const float* __restrict__ w_field,
        const float* __restrict__ b_field,
        const float* __restrict__ gates,
        const float* __restrict__ w_mix,
        const float* __restrict__ b_mix,
        float* __restrict__ ws) {
    int i = blockIdx.x * 256 + threadIdx.x;    // grid 32*256 = 8192
    // Bt[n][k] bf16, k = c*8 + t, value = sigmoid(gates[t]) * w_mix[n, t*32+c]
    {
        int n = i >> 8, k = i & 255, c = k >> 3, t = k & 7;
        float sg = 1.0f / (1.0f + expf(-gates[t]));
        ((unsigned short*)(ws + WS_BT_F))[n * 256 + k] = f2bf(sg * w_mix[n * 256 + t * 32 + c]);
    }
    if (i < 384) { int c = i / 12, o = i - c * 12; ws[WS_WF + i] = w_field[o * 32 + c]; }
    if (i < 12)  ws[WS_BF + i] = b_field[i];
    if (i < 32)  ws[WS_BM + i] = b_mix[i];
}

__global__ __launch_bounds__(256) void geo_main(
        const float* __restrict__ x,
        const float* __restrict__ ws,
        float* __restrict__ out) {
    __shared__ __align__(16) char smem[SMEM_SZ];
    char* tokb  = smem + TOK_OFF;
    h2*   tileP = (h2*)(smem + TILE_OFF);      // word-indexed, 2 planes of TILE_WSTR
    float* cbuf = (float*)smem;                // alias, post-loop only

    const int tid = threadIdx.x;
    const int b  = blockIdx.x;
    const int bx = b % 6, by = (b / 6) % 6, bz = (b / 36) % 12, n = b / 432;
    const int lx = tid & 7, ly = (tid >> 3) & 7, lz = tid >> 6;
    const int w = bx * 8 + lx, h = by * 8 + ly, d = bz * 4 + lz;
    const int xlo = bx * 8 - 2, ylo = by * 8 - 2, zlo = bz * 4 - 2;
    const int lane = tid & 63, w64 = tid & 192;

    const float* xn = x + (size_t)n * CH * DHW;

    // ---- channel-invariant halo-load offsets ----
    int goff[6];
#pragma unroll
    for (int i = 0; i < 6; ++i) {
        int e  = tid + i * 256;
        int ee = (e < TILE_N) ? e : 0;
        int tz = ee / 169; int r0 = ee - tz * 169;
        int ty = r0 / 13;  int tx = r0 - ty * 13;
        int zg = min(max(zlo + tz, 0), 47);
        int yg = min(max(ylo + ty, 0), 47);
        int xg = min(max(xlo + tx, 0), 47);
        goff[i] = (zg * 48 + yg) * 48 + xg;
    }

    // ---- phase A: f[12] = w_field @ x(:,pos) + b_field ----
    const int pos = (d * 48 + h) * 48 + w;
    float f[12];
#pragma unroll
    for (int o = 0; o < 12; ++o) f[o] = ws[WS_BF + o];
    for (int c = 0; c < CH; ++c) {
        float xv = xn[c * DHW + pos];
        const float* wf = ws + WS_WF + c * 12;
#pragma unroll
        for (int o = 0; o < 12; ++o) f[o] = fmaf(wf[o], xv, f[o]);
    }

    // ---- per-voxel sample parameters ----
    h2 fx2[6], fy2[6], fz2[6];
    int a00[6], a01[6], a10[6], a11[6];
    float uxk[3], uyk[3], uzk[3], irk[3], ir2k[3];
    const float cscale = 48.0f / (48.0f + EPSF);
#pragma unroll
    for (int k = 0; k < 3; ++k) {
        float vx = f[4*k], vy = f[4*k+1], vz = f[4*k+2], s = f[4*k+3];
        float inv = 1.0f / sqrtf(vx*vx + vy*vy + vz*vz + EPSF);
        float ux = vx * inv, uy = vy * inv, uz = vz * inv;
        float r  = 0.5f + 1.5f / (1.0f + expf(-s));
        uxk[k] = ux; uyk[k] = uy; uzk[k] = uz;
        float ir = 1.0f / (r + EPSF); irk[k] = ir; ir2k[k] = ir * ir;
#pragma unroll
        for (int sgn = 0; sgn < 2; ++sgn) {
            int   si = 2 * k + sgn;
            float sf = sgn ? -1.0f : 1.0f;
            float txr = (float)w + sf * r * ux * cscale;
            float tyr = (float)h + sf * r * uy * cscale;
            float tzr = (float)d + sf * r * uz * cscale;
            float cx = fabsf(txr + 0.5f); float ix = fminf(cx, 96.0f - cx) - 0.5f;
            float cy = fabsf(tyr + 0.5f); float iy = fminf(cy, 96.0f - cy) - 0.5f;
            float cz = fabsf(tzr + 0.5f); float iz = fminf(cz, 96.0f - cz) - 0.5f;
            float x0f = floorf(ix), y0f = floorf(iy), z0f = floorf(iz);
            float fx = ix - x0f, fy = iy - y0f, fz = iz - z0f;
            int x0 = min(max((int)x0f, 0), 47); int x1 = min(x0 + 1, 47);
            int y0 = min(max((int)y0f, 0), 47); int y1 = min(y0 + 1, 47);
            int z0 = min(max((int)z0f, 0), 47); int z1 = min(z0 + 1, 47);
            float fxe = (x1 == x0) ? 0.0f : fx;  // reference's clipped-x1 semantics
            _Float16 hx = (_Float16)fxe, hy = (_Float16)fy, hz = (_Float16)fz;
            fx2[si] = (h2){hx, hx}; fy2[si] = (h2){hy, hy}; fz2[si] = (h2){hz, hz};
            int lz0 = z0 - zlo, lz1 = z1 - zlo;
            int ly0 = y0 - ylo, ly1 = y1 - ylo;
            int lx0 = x0 - xlo;
            a00[si] = (lz0 * 13 + ly0) * 13 + lx0;
            a01[si] = (lz0 * 13 + ly1) * 13 + lx0;
            a10[si] = (lz1 * 13 + ly0) * 13 + lx0;
            a11[si] = (lz1 * 13 + ly1) * 13 + lx0;
        }
    }

    // ---- stage group 0 tiles (2 planes of fp16 pairs) + zero pad words ----
    if (tid == 0) { tileP[TILE_N] = (h2){0, 0}; tileP[TILE_WSTR + TILE_N] = (h2){0, 0}; }
    {
        float ld[24];
#pragma unroll
        for (int cg = 0; cg < 4; ++cg) {
            const float* xc = xn + cg * DHW;
#pragma unroll
            for (int i = 0; i < 6; ++i) ld[cg * 6 + i] = xc[goff[i]];
        }
#pragma unroll
        for (int p = 0; p < 2; ++p)
#pragma unroll
            for (int i = 0; i < 6; ++i) {
                int e = tid + i * 256;
                if (e < TILE_N)
                    tileP[p * TILE_WSTR + e] = pkrtz(ld[(2*p) * 6 + i], ld[(2*p+1) * 6 + i]);
            }
    }
    __syncthreads();

    floatx4 acc[4][2];
#pragma unroll
    for (int mt = 0; mt < 4; ++mt)
#pragma unroll
        for (int nt = 0; nt < 2; ++nt) acc[mt][nt] = (floatx4){0.f, 0.f, 0.f, 0.f};

    const int self = ((lz + 2) * 13 + (ly + 2)) * 13 + (lx + 2);
    const unsigned short* bt = (const unsigned short*)(ws + WS_BT_F);
    const int tokq = (tid >> 3) & 3;           // token-quadrant swizzle key

    for (int g = 0; g < GROUPS; ++g) {
        float nld[24];
        if (g < GROUPS - 1) {
            const float* xg = xn + (g + 1) * 4 * DHW;
#pragma unroll
            for (int cg = 0; cg < 4; ++cg) {
                const float* xc = xg + cg * DHW;
#pragma unroll
                for (int i = 0; i < 6; ++i) nld[cg * 6 + i] = xc[goff[i]];
            }
        }
        // ---- packed trilinear: 2 channels per plane, 2 planes ----
#pragma unroll
        for (int p = 0; p < 2; ++p) {
            const h2* tb = tileP + p * TILE_WSTR;
            h2 s2 = tb[self];
            h2 v2[6];
#pragma unroll
            for (int si = 0; si < 6; ++si) {
                int b00 = a00[si], b01 = a01[si], b10 = a10[si], b11 = a11[si];
                h2 v000 = tb[b00], v001 = tb[b00 + 1];
                h2 v010 = tb[b01], v011 = tb[b01 + 1];
                h2 v100 = tb[b10], v101 = tb[b10 + 1];
                h2 v110 = tb[b11], v111 = tb[b11 + 1];
                h2 c00 = v000 + fx2[si] * (v001 - v000);
                h2 c01 = v010 + fx2[si] * (v011 - v010);
                h2 c10 = v100 + fx2[si] * (v101 - v100);
                h2 c11 = v110 + fx2[si] * (v111 - v110);
                h2 c0  = c00 + fy2[si] * (c01 - c00);
                h2 c1  = c10 + fy2[si] * (c11 - c10);
                v2[si] = c0 + fz2[si] * (c1 - c0);
            }
            // ---- per-channel token assembly (fp32) ----
#pragma unroll
            for (int sub = 0; sub < 2; ++sub) {
                float xv = sub ? (float)s2.y : (float)s2.x;
                float val[6];
#pragma unroll
                for (int si = 0; si < 6; ++si)
                    val[si] = sub ? (float)v2[si].y : (float)v2[si].x;
                float t1, t2, t3, gx, gy, gz, l;
                {
                    float sp, sm, d1;
                    sp = val[0]; sm = val[1]; t1 = 0.5f * (sp + sm);
                    d1 = 0.5f * (sp - sm) * irk[0];
                    gx = uxk[0] * d1; gy = uyk[0] * d1; gz = uzk[0] * d1;
                    l  = (sp + sm - 2.0f * xv) * ir2k[0];
                    sp = val[2]; sm = val[3]; t2 = 0.5f * (sp + sm);
                    d1 = 0.5f * (sp - sm) * irk[1];
                    gx = fmaf(uxk[1], d1, gx); gy = fmaf(uyk[1], d1, gy); gz = fmaf(uzk[1], d1, gz);
                    l  = fmaf(sp + sm - 2.0f * xv, ir2k[1], l);
                    sp = val[4]; sm = val[5]; t3 = 0.5f * (sp + sm);
                    d1 = 0.5f * (sp - sm) * irk[2];
                    gx = fmaf(uxk[2], d1, gx); gy = fmaf(uyk[2], d1, gy); gz = fmaf(uzk[2], d1, gz);
                    l  = fmaf(sp + sm - 2.0f * xv, ir2k[2], l);
                }
                uint4 tw;
                tw.x = pk2(xv, t1);
                tw.y = pk2(t2, t3);
                tw.z = pk2(gx, gy);
                tw.w = pk2(gz, l * (1.0f / 3.0f));
                int cg = 2 * p + sub;
                int qe = cg ^ tokq;            // bank-conflict-free token write
                *(uint4*)(tokb + tid * TOK_STR + qe * 16) = tw;
            }
        }
        __syncthreads();   // tokens visible; tile reads complete

        if (g < GROUPS - 1) {
#pragma unroll
            for (int p = 0; p < 2; ++p)
#pragma unroll
                for (int i = 0; i < 6; ++i) {
                    int e = tid + i * 256;
                    if (e < TILE_N)
                        tileP[p * TILE_WSTR + e] = pkrtz(nld[(2*p) * 6 + i], nld[(2*p+1) * 6 + i]);
                }
        }
        // ---- MFMA: K-chunk g (k = g*32 .. g*32+31) ----
        int q = lane >> 4, nlo = lane & 15;
        short8 b0 = *(const short8*)(bt + (nlo * 256 + g * 32 + q * 8));
        short8 b1 = *(const short8*)(bt + ((nlo + 16) * 256 + g * 32 + q * 8));
#pragma unroll
        for (int mt = 0; mt < 4; ++mt) {
            int row = w64 + mt * 16 + nlo;
            int qe  = q ^ ((row >> 3) & 3);
            short8 a = *(const short8*)(tokb + row * TOK_STR + qe * 16);
            acc[mt][0] = __builtin_amdgcn_mfma_f32_16x16x32_bf16(a, b0, acc[mt][0], 0, 0, 0);
            acc[mt][1] = __builtin_amdgcn_mfma_f32_16x16x32_bf16(a, b1, acc[mt][1], 0, 0, 0);
        }
        __syncthreads();   // tile writes visible; token reads complete
    }

    // ---- C writeback via LDS (col-swizzled, conflict-free) ----
    {
        int q = lane >> 4, nlo = lane & 15;
#pragma unroll
        for (int mt = 0; mt < 4; ++mt)
#pragma unroll
            for (int nt = 0; nt < 2; ++nt)
#pragma unroll
                for (int r = 0; r < 4; ++r) {
                    int v = w64 + mt * 16 + q * 4 + r;
                    int col = nt * 16 + nlo;
                    cbuf[v * 36 + (col ^ (v & 31))] = acc[mt][nt][r];
                }
    }
    __syncthreads();

    // ---- epilogue: out = x + delta + b_mix (coalesced) ----
    const float* dr = cbuf + tid * 36;
    float* on = out + (size_t)n * CH * DHW;
#pragma unroll
    for (int o = 0; o < 32; ++o)
        on[o * DHW + pos] = xn[o * DHW + pos] + dr[o ^ (tid & 31)] + ws[WS_BM + o];
}

extern "C" void kernel_launch(void* const* d_in, const int* in_sizes, int n_in,
                              void* d_out, int out_size, void* d_ws, size_t ws_size,
                              hipStream_t stream) {
    const float *x = (const float*)d_in[0], *w_field = (const float*)d_in[1],
                *b_field = (const float*)d_in[2], *gates = (const float*)d_in[3],
                *w_mix = (const float*)d_in[4], *b_mix = (const float*)d_in[5];
    for (int i = 0; i < n_in; ++i) {
        switch (in_sizes[i]) {
            case NB * CH * DHW: x       = (const float*)d_in[i]; break;
            case 12 * CH:       w_field = (const float*)d_in[i]; break;
            case 12:            b_field = (const float*)d_in[i]; break;
            case TT:            gates   = (const float*)d_in[i]; break;
            case CH * TT * CH:  w_mix   = (const float*)d_in[i]; break;
            case CH:            b_mix   = (const float*)d_in[i]; break;
            default: break;
        }
    }
    float* ws = (float*)d_ws;
    prep_kernel<<<32, 256, 0, stream>>>(w_field, b_field, gates, w_mix, b_mix, ws);
    geo_main<<<864, 256, 0, stream>>>(x, ws, (float*)d_out);
}

// Round 10
// 161.839 us; speedup vs baseline: 2.7816x; 1.1019x over previous
//
#include <hip/hip_runtime.h>
#include <math.h>

// (N,C,D,H,W)=(2,32,48,48,48), K=3, T=8. All fp32 in/out (verified R5).
// R10 = R9 + XCD-locality block swizzle: blockIdx&7 (presumed XCD) owns a
// contiguous 108-block chunk (one batch, 3 z-slabs, ~4.7MB slab; ~0.6MB per
// channel-group) so halo re-reads hit per-XCD L2 instead of crossing to L3.
// Theory: R6/R9 both pinned at 125us == FETCH 223MB @ ~2TB/s TCC-miss path.
// Also: nontemporal epilogue stores (out never re-read).
#define NB   2
#define CH   32
#define DHW  (48*48*48)
#define TT   8
#define EPSF 1e-6f

#define TILE_N   1521            // 13*13*9 halo tile (voxel words; 1 word = 2 ch fp16)
#define TILE_WSTR 1522           // words per plane (+1 pad)
#define GROUPS   8               // 32 ch / 4 per group (= 2 pair-planes)

// LDS layout (bytes): tokens [0,20480) = 256*80 ; tile pairs [20480,32656)
// cbuf aliases [0,36864) = 256 rows * 36 floats (used only after final barrier)
#define TOK_OFF  0
#define TOK_STR  80              // 64B tokens + 16B pad
#define TILE_OFF 20480
#define SMEM_SZ  36864

// ws layout (float idx): Bt bf16 [0,4096) floats (=8192 ushort), wf 4096, bf 4480, bm 4492
#define WS_BT_F 0
#define WS_WF   4096
#define WS_BF   4480
#define WS_BM   4492

typedef __attribute__((ext_vector_type(8))) short short8;
typedef __attribute__((ext_vector_type(4))) float floatx4;
typedef __attribute__((ext_vector_type(2))) _Float16 h2;

__device__ __forceinline__ h2 pkrtz(float a, float b) {
    return __builtin_bit_cast(h2, __builtin_amdgcn_cvt_pkrtz(a, b));
}
__device__ __forceinline__ unsigned short f2bf(float f) {
    unsigned u = __float_as_uint(f);
    u += 0x7FFFu + ((u >> 16) & 1u);           // RNE
    return (unsigned short)(u >> 16);
}
__device__ __forceinline__ unsigned pk2(float a, float b) {
    return (unsigned)f2bf(a) | ((unsigned)f2bf(b) << 16);
}

__global__ __launch_bounds__(256) void prep_kernel(
        const float* __restrict__ w_field,
        const float* __restrict__ b_field,
        const float* __restrict__ gates,
        const float* __restrict__ w_mix,
        const float* __restrict__ b_mix,
        float* __restrict__ ws) {
    int i = blockIdx.x * 256 + threadIdx.x;    // grid 32*256 = 8192
    // Bt[n][k] bf16, k = c*8 + t, value = sigmoid(gates[t]) * w_mix[n, t*32+c]
    {
        int n = i >> 8, k = i & 255, c = k >> 3, t = k & 7;
        float sg = 1.0f / (1.0f + expf(-gates[t]));
        ((unsigned short*)(ws + WS_BT_F))[n * 256 + k] = f2bf(sg * w_mix[n * 256 + t * 32 + c]);
    }
    if (i < 384) { int c = i / 12, o = i - c * 12; ws[WS_WF + i] = w_field[o * 32 + c]; }
    if (i < 12)  ws[WS_BF + i] = b_field[i];
    if (i < 32)  ws[WS_BM + i] = b_mix[i];
}

__global__ __launch_bounds__(256) void geo_main(
        const float* __restrict__ x,
        const float* __restrict__ ws,
        float* __restrict__ out) {
    __shared__ __align__(16) char smem[SMEM_SZ];
    char* tokb  = smem + TOK_OFF;
    h2*   tileP = (h2*)(smem + TILE_OFF);      // word-indexed, 2 planes of TILE_WSTR
    float* cbuf = (float*)smem;                // alias, post-loop only

    const int tid = threadIdx.x;
    // XCD-locality swizzle: chunk c = blockIdx&7 (presumed XCD via round-robin
    // dispatch) gets lin in [108c, 108(c+1)) -> one batch, 3 contiguous z-slabs.
    const int lin = (blockIdx.x & 7) * 108 + (blockIdx.x >> 3);
    const int bx = lin % 6, by = (lin / 6) % 6, bz = (lin / 36) % 12, n = lin / 432;
    const int lx = tid & 7, ly = (tid >> 3) & 7, lz = tid >> 6;
    const int w = bx * 8 + lx, h = by * 8 + ly, d = bz * 4 + lz;
    const int xlo = bx * 8 - 2, ylo = by * 8 - 2, zlo = bz * 4 - 2;
    const int lane = tid & 63, w64 = tid & 192;

    const float* xn = x + (size_t)n * CH * DHW;

    // ---- channel-invariant halo-load offsets ----
    int goff[6];
#pragma unroll
    for (int i = 0; i < 6; ++i) {
        int e  = tid + i * 256;
        int ee = (e < TILE_N) ? e : 0;
        int tz = ee / 169; int r0 = ee - tz * 169;
        int ty = r0 / 13;  int tx = r0 - ty * 13;
        int zg = min(max(zlo + tz, 0), 47);
        int yg = min(max(ylo + ty, 0), 47);
        int xg = min(max(xlo + tx, 0), 47);
        goff[i] = (zg * 48 + yg) * 48 + xg;
    }

    // ---- phase A: f[12] = w_field @ x(:,pos) + b_field ----
    const int pos = (d * 48 + h) * 48 + w;
    float f[12];
#pragma unroll
    for (int o = 0; o < 12; ++o) f[o] = ws[WS_BF + o];
    for (int c = 0; c < CH; ++c) {
        float xv = xn[c * DHW + pos];
        const float* wf = ws + WS_WF + c * 12;
#pragma unroll
        for (int o = 0; o < 12; ++o) f[o] = fmaf(wf[o], xv, f[o]);
    }

    // ---- per-voxel sample parameters ----
    h2 fx2[6], fy2[6], fz2[6];
    int a00[6], a01[6], a10[6], a11[6];
    float uxk[3], uyk[3], uzk[3], irk[3], ir2k[3];
    const float cscale = 48.0f / (48.0f + EPSF);
#pragma unroll
    for (int k = 0; k < 3; ++k) {
        float vx = f[4*k], vy = f[4*k+1], vz = f[4*k+2], s = f[4*k+3];
        float inv = 1.0f / sqrtf(vx*vx + vy*vy + vz*vz + EPSF);
        float ux = vx * inv, uy = vy * inv, uz = vz * inv;
        float r  = 0.5f + 1.5f / (1.0f + expf(-s));
        uxk[k] = ux; uyk[k] = uy; uzk[k] = uz;
        float ir = 1.0f / (r + EPSF); irk[k] = ir; ir2k[k] = ir * ir;
#pragma unroll
        for (int sgn = 0; sgn < 2; ++sgn) {
            int   si = 2 * k + sgn;
            float sf = sgn ? -1.0f : 1.0f;
            float txr = (float)w + sf * r * ux * cscale;
            float tyr = (float)h + sf * r * uy * cscale;
            float tzr = (float)d + sf * r * uz * cscale;
            float cx = fabsf(txr + 0.5f); float ix = fminf(cx, 96.0f - cx) - 0.5f;
            float cy = fabsf(tyr + 0.5f); float iy = fminf(cy, 96.0f - cy) - 0.5f;
            float cz = fabsf(tzr + 0.5f); float iz = fminf(cz, 96.0f - cz) - 0.5f;
            float x0f = floorf(ix), y0f = floorf(iy), z0f = floorf(iz);
            float fx = ix - x0f, fy = iy - y0f, fz = iz - z0f;
            int x0 = min(max((int)x0f, 0), 47); int x1 = min(x0 + 1, 47);
            int y0 = min(max((int)y0f, 0), 47); int y1 = min(y0 + 1, 47);
            int z0 = min(max((int)z0f, 0), 47); int z1 = min(z0 + 1, 47);
            float fxe = (x1 == x0) ? 0.0f : fx;  // reference's clipped-x1 semantics
            _Float16 hx = (_Float16)fxe, hy = (_Float16)fy, hz = (_Float16)fz;
            fx2[si] = (h2){hx, hx}; fy2[si] = (h2){hy, hy}; fz2[si] = (h2){hz, hz};
            int lz0 = z0 - zlo, lz1 = z1 - zlo;
            int ly0 = y0 - ylo, ly1 = y1 - ylo;
            int lx0 = x0 - xlo;
            a00[si] = (lz0 * 13 + ly0) * 13 + lx0;
            a01[si] = (lz0 * 13 + ly1) * 13 + lx0;
            a10[si] = (lz1 * 13 + ly0) * 13 + lx0;
            a11[si] = (lz1 * 13 + ly1) * 13 + lx0;
        }
    }

    // ---- stage group 0 tiles (2 planes of fp16 pairs) + zero pad words ----
    if (tid == 0) { tileP[TILE_N] = (h2){0, 0}; tileP[TILE_WSTR + TILE_N] = (h2){0, 0}; }
    {
        float ld[24];
#pragma unroll
        for (int cg = 0; cg < 4; ++cg) {
            const float* xc = xn + cg * DHW;
#pragma unroll
            for (int i = 0; i < 6; ++i) ld[cg * 6 + i] = xc[goff[i]];
        }
#pragma unroll
        for (int p = 0; p < 2; ++p)
#pragma unroll
            for (int i = 0; i < 6; ++i) {
                int e = tid + i * 256;
                if (e < TILE_N)
                    tileP[p * TILE_WSTR + e] = pkrtz(ld[(2*p) * 6 + i], ld[(2*p+1) * 6 + i]);
            }
    }
    __syncthreads();

    floatx4 acc[4][2];
#pragma unroll
    for (int mt = 0; mt < 4; ++mt)
#pragma unroll
        for (int nt = 0; nt < 2; ++nt) acc[mt][nt] = (floatx4){0.f, 0.f, 0.f, 0.f};

    const int self = ((lz + 2) * 13 + (ly + 2)) * 13 + (lx + 2);
    const unsigned short* bt = (const unsigned short*)(ws + WS_BT_F);
    const int tokq = (tid >> 3) & 3;           // token-quadrant swizzle key

    for (int g = 0; g < GROUPS; ++g) {
        float nld[24];
        if (g < GROUPS - 1) {
            const float* xg = xn + (g + 1) * 4 * DHW;
#pragma unroll
            for (int cg = 0; cg < 4; ++cg) {
                const float* xc = xg + cg * DHW;
#pragma unroll
                for (int i = 0; i < 6; ++i) nld[cg * 6 + i] = xc[goff[i]];
            }
        }
        // ---- packed trilinear: 2 channels per plane, 2 planes ----
#pragma unroll
        for (int p = 0; p < 2; ++p) {
            const h2* tb = tileP + p * TILE_WSTR;
            h2 s2 = tb[self];
            h2 v2[6];
#pragma unroll
            for (int si = 0; si < 6; ++si) {
                int b00 = a00[si], b01 = a01[si], b10 = a10[si], b11 = a11[si];
                h2 v000 = tb[b00], v001 = tb[b00 + 1];
                h2 v010 = tb[b01], v011 = tb[b01 + 1];
                h2 v100 = tb[b10], v101 = tb[b10 + 1];
                h2 v110 = tb[b11], v111 = tb[b11 + 1];
                h2 c00 = v000 + fx2[si] * (v001 - v000);
                h2 c01 = v010 + fx2[si] * (v011 - v010);
                h2 c10 = v100 + fx2[si] * (v101 - v100);
                h2 c11 = v110 + fx2[si] * (v111 - v110);
                h2 c0  = c00 + fy2[si] * (c01 - c00);
                h2 c1  = c10 + fy2[si] * (c11 - c10);
                v2[si] = c0 + fz2[si] * (c1 - c0);
            }
            // ---- per-channel token assembly (fp32) ----
#pragma unroll
            for (int sub = 0; sub < 2; ++sub) {
                float xv = sub ? (float)s2.y : (float)s2.x;
                float val[6];
#pragma unroll
                for (int si = 0; si < 6; ++si)
                    val[si] = sub ? (float)v2[si].y : (float)v2[si].x;
                float t1, t2, t3, gx, gy, gz, l;
                {
                    float sp, sm, d1;
                    sp = val[0]; sm = val[1]; t1 = 0.5f * (sp + sm);
                    d1 = 0.5f * (sp - sm) * irk[0];
                    gx = uxk[0] * d1; gy = uyk[0] * d1; gz = uzk[0] * d1;
                    l  = (sp + sm - 2.0f * xv) * ir2k[0];
                    sp = val[2]; sm = val[3]; t2 = 0.5f * (sp + sm);
                    d1 = 0.5f * (sp - sm) * irk[1];
                    gx = fmaf(uxk[1], d1, gx); gy = fmaf(uyk[1], d1, gy); gz = fmaf(uzk[1], d1, gz);
                    l  = fmaf(sp + sm - 2.0f * xv, ir2k[1], l);
                    sp = val[4]; sm = val[5]; t3 = 0.5f * (sp + sm);
                    d1 = 0.5f * (sp - sm) * irk[2];
                    gx = fmaf(uxk[2], d1, gx); gy = fmaf(uyk[2], d1, gy); gz = fmaf(uzk[2], d1, gz);
                    l  = fmaf(sp + sm - 2.0f * xv, ir2k[2], l);
                }
                uint4 tw;
                tw.x = pk2(xv, t1);
                tw.y = pk2(t2, t3);
                tw.z = pk2(gx, gy);
                tw.w = pk2(gz, l * (1.0f / 3.0f));
                int cg = 2 * p + sub;
                int qe = cg ^ tokq;            // bank-conflict-free token write
                *(uint4*)(tokb + tid * TOK_STR + qe * 16) = tw;
            }
        }
        __syncthreads();   // tokens visible; tile reads complete

        if (g < GROUPS - 1) {
#pragma unroll
            for (int p = 0; p < 2; ++p)
#pragma unroll
                for (int i = 0; i < 6; ++i) {
                    int e = tid + i * 256;
                    if (e < TILE_N)
                        tileP[p * TILE_WSTR + e] = pkrtz(nld[(2*p) * 6 + i], nld[(2*p+1) * 6 + i]);
                }
        }
        // ---- MFMA: K-chunk g (k = g*32 .. g*32+31) ----
        int q = lane >> 4, nlo = lane & 15;
        short8 b0 = *(const short8*)(bt + (nlo * 256 + g * 32 + q * 8));
        short8 b1 = *(const short8*)(bt + ((nlo + 16) * 256 + g * 32 + q * 8));
#pragma unroll
        for (int mt = 0; mt < 4; ++mt) {
            int row = w64 + mt * 16 + nlo;
            int qe  = q ^ ((row >> 3) & 3);
            short8 a = *(const short8*)(tokb + row * TOK_STR + qe * 16);
            acc[mt][0] = __builtin_amdgcn_mfma_f32_16x16x32_bf16(a, b0, acc[mt][0], 0, 0, 0);
            acc[mt][1] = __builtin_amdgcn_mfma_f32_16x16x32_bf16(a, b1, acc[mt][1], 0, 0, 0);
        }
        __syncthreads();   // tile writes visible; token reads complete
    }

    // ---- C writeback via LDS (col-swizzled, conflict-free) ----
    {
        int q = lane >> 4, nlo = lane & 15;
#pragma unroll
        for (int mt = 0; mt < 4; ++mt)
#pragma unroll
            for (int nt = 0; nt < 2; ++nt)
#pragma unroll
                for (int r = 0; r < 4; ++r) {
                    int v = w64 + mt * 16 + q * 4 + r;
                    int col = nt * 16 + nlo;
                    cbuf[v * 36 + (col ^ (v & 31))] = acc[mt][nt][r];
                }
    }
    __syncthreads();

    // ---- epilogue: out = x + delta + b_mix (coalesced, nontemporal) ----
    const float* dr = cbuf + tid * 36;
    float* on = out + (size_t)n * CH * DHW;
#pragma unroll
    for (int o = 0; o < 32; ++o)
        __builtin_nontemporal_store(
            xn[o * DHW + pos] + dr[o ^ (tid & 31)] + ws[WS_BM + o],
            on + o * DHW + pos);
}

extern "C" void kernel_launch(void* const* d_in, const int* in_sizes, int n_in,
                              void* d_out, int out_size, void* d_ws, size_t ws_size,
                              hipStream_t stream) {
    const float *x = (const float*)d_in[0], *w_field = (const float*)d_in[1],
                *b_field = (const float*)d_in[2], *gates = (const float*)d_in[3],
                *w_mix = (const float*)d_in[4], *b_mix = (const float*)d_in[5];
    for (int i = 0; i < n_in; ++i) {
        switch (in_sizes[i]) {
            case NB * CH * DHW: x       = (const float*)d_in[i]; break;
            case 12 * CH:       w_field = (const float*)d_in[i]; break;
            case 12:            b_field = (const float*)d_in[i]; break;
            case TT:            gates   = (const float*)d_in[i]; break;
            case CH * TT * CH:  w_mix   = (const float*)d_in[i]; break;
            case CH:            b_mix   = (const float*)d_in[i]; break;
            default: break;
        }
    }
    float* ws = (float*)d_ws;
    prep_kernel<<<32, 256, 0, stream>>>(w_field, b_field, gates, w_mix, b_mix, ws);
    geo_main<<<864, 256, 0, stream>>>(x, ws, (float*)d_out);
}